// Round 13
// baseline (180.733 us; speedup 1.0000x reference)
//
#include <hip/hip_runtime.h>
#include <hip/hip_bf16.h>
#include <cstdint>

// Problem constants: B=2, T=2048, D_IN=D_OUT=1024, H=16, DH=64
#define SEQ_T 2048
#define DMODEL 1024
#define NHEAD 16
#define DHEAD 64

typedef __attribute__((ext_vector_type(8))) __bf16 bf16x8;
typedef __attribute__((ext_vector_type(4))) float floatx4;

static __device__ __forceinline__ uint16_t f2bf(float f) {
    union { float f; uint32_t u; } v; v.f = f;
    uint32_t r = v.u + 0x7FFFu + ((v.u >> 16) & 1u);   // RNE
    return (uint16_t)(r >> 16);
}

// -------- merged fp32->bf16 converts: z<4 weight transpose, z==4 x --------
// W_q (z==0) pre-scaled by 0.125*log2(e): QK^T emits s*C directly, so the
// attention softmax is a single raw v_exp_f32 (__builtin_amdgcn_exp2f).
__global__ void mha_cvt(const float* __restrict__ x, uint16_t* __restrict__ xb,
                        const float* __restrict__ W0, const float* __restrict__ W1,
                        const float* __restrict__ W2, const float* __restrict__ W3,
                        uint16_t* __restrict__ T0, uint16_t* __restrict__ T1,
                        uint16_t* __restrict__ T2, uint16_t* __restrict__ T3) {
    if (blockIdx.z == 4) {
        int base = (blockIdx.y * 16 + blockIdx.x) * 256 + threadIdx.x;
#pragma unroll
        for (int i = 0; i < 16; ++i) {
            int idx = base + i * 65536;
            float4 f = ((const float4*)x)[idx];
            union { uint16_t u[4]; uint64_t v; } o;
            o.u[0] = f2bf(f.x); o.u[1] = f2bf(f.y); o.u[2] = f2bf(f.z); o.u[3] = f2bf(f.w);
            ((uint64_t*)xb)[idx] = o.v;
        }
        return;
    }
    const float* W; uint16_t* Tt; float sc;
    switch (blockIdx.z) {
        case 0: W = W0; Tt = T0; sc = 0.125f * 1.44269504089f; break;
        case 1: W = W1; Tt = T1; sc = 1.f; break;
        case 2: W = W2; Tt = T2; sc = 1.f; break;
        default: W = W3; Tt = T3; sc = 1.f; break;
    }
    __shared__ float tile[64][65];
    const int c  = threadIdx.x & 63;
    const int r0 = threadIdx.x >> 6;
    const int R0 = blockIdx.y * 64, C0 = blockIdx.x * 64;
#pragma unroll
    for (int rr = 0; rr < 16; ++rr) {
        int r = r0 + rr * 4;
        tile[r][c] = W[(size_t)(R0 + r) * DMODEL + C0 + c];
    }
    __syncthreads();
#pragma unroll
    for (int rr = 0; rr < 16; ++rr) {
        int r = r0 + rr * 4;
        Tt[(size_t)(C0 + r) * DMODEL + R0 + c] = f2bf(tile[c][r] * sc);
    }
}

// ------ bf16 MFMA GEMM, 64M x 128N tile, BK=64, B^T input, swizzled ------
// (R10/R12-proven shape; qkv grid 1536 = 6 blocks/CU @ 24 KB dynamic LDS.)
// Swizzle: row r slot q' holds source sub-chunk q'^(r&7) -> 2-way-only.
// MODE 0: bf16 row-major out. MODE 1: Vt[(b*1024+col)*2048+t] via LDS
// transpose reusing staging smem.
template<int MODE>
__device__ __forceinline__ void gemm_bk64_body(
    const uint16_t* __restrict__ A, const uint16_t* __restrict__ Bt,
    uint16_t* __restrict__ outB) {
    const int K = DMODEL, N = DMODEL;
    extern __shared__ char smem[];                  // 24576 B dynamic
    uint16_t* As = (uint16_t*)smem;                 // [64][64]  8 KB
    uint16_t* Bs = (uint16_t*)(smem + 8192);        // [128][64] 16 KB
    const int tid  = threadIdx.x;
    const int wave = tid >> 6;
    const int lane = tid & 63;
    const int m0 = blockIdx.y * 64;
    const int n0 = blockIdx.x * 128;
    const int lr   = lane & 15;
    const int quad = lane >> 4;

    floatx4 acc[4][2];
#pragma unroll
    for (int i = 0; i < 4; ++i)
#pragma unroll
        for (int j = 0; j < 2; ++j) acc[i][j] = (floatx4)0.0f;

    for (int k0 = 0; k0 < K; k0 += 64) {
#pragma unroll
        for (int i = 0; i < 2; ++i) {               // A: 512 chunks (16B)
            int c = i * 256 + tid;
            int r = c >> 3, s = (c & 7) ^ (r & 7);
            const uint16_t* g = A + (size_t)(m0 + r) * K + k0 + s * 8;
            __builtin_amdgcn_global_load_lds((const __attribute__((address_space(1))) void*)g,
                                             (__attribute__((address_space(3))) void*)(As + (size_t)c * 8), 16, 0, 0);
        }
#pragma unroll
        for (int i = 0; i < 4; ++i) {               // B: 1024 chunks
            int c = i * 256 + tid;
            int r = c >> 3, s = (c & 7) ^ (r & 7);
            const uint16_t* g = Bt + (size_t)(n0 + r) * K + k0 + s * 8;
            __builtin_amdgcn_global_load_lds((const __attribute__((address_space(1))) void*)g,
                                             (__attribute__((address_space(3))) void*)(Bs + (size_t)c * 8), 16, 0, 0);
        }
        __syncthreads();
#pragma unroll
        for (int ks = 0; ks < 2; ++ks) {            // two 32-wide k-halves
            bf16x8 af[4], bfr[2];
#pragma unroll
            for (int mi = 0; mi < 4; ++mi) {
                int row = mi * 16 + lr;
                af[mi] = *(const bf16x8*)&As[row * 64 + (((ks * 4 + quad) ^ (row & 7)) << 3)];
            }
#pragma unroll
            for (int ni = 0; ni < 2; ++ni) {
                int row = wave * 32 + ni * 16 + lr;
                bfr[ni] = *(const bf16x8*)&Bs[row * 64 + (((ks * 4 + quad) ^ (row & 7)) << 3)];
            }
#pragma unroll
            for (int mi = 0; mi < 4; ++mi)
#pragma unroll
                for (int ni = 0; ni < 2; ++ni)
                    acc[mi][ni] = __builtin_amdgcn_mfma_f32_16x16x32_bf16(af[mi], bfr[ni], acc[mi][ni], 0, 0, 0);
        }
        __syncthreads();
    }
    if constexpr (MODE == 1) {
        uint16_t* Ct = (uint16_t*)smem;             // [128][72], 18.4 KB
        const int bb = m0 >> 11, t0 = m0 & 2047;
#pragma unroll
        for (int mi = 0; mi < 4; ++mi)
#pragma unroll
            for (int ni = 0; ni < 2; ++ni) {
                int cl = wave * 32 + ni * 16 + lr;
                int tl = mi * 16 + quad * 4;
                int tls = tl ^ ((cl & 3) << 4);     // 2-way-only bank pattern
                union { uint16_t u[4]; uint64_t v8; } pk;
#pragma unroll
                for (int r = 0; r < 4; ++r) pk.u[r] = f2bf(acc[mi][ni][r]);
                *(uint64_t*)&Ct[cl * 72 + tls] = pk.v8;
            }
        __syncthreads();
#pragma unroll
        for (int k = 0; k < 4; ++k) {
            int c = k * 256 + tid;                  // 1024 chunks of 16B
            int cl = c >> 3, off = (c & 7) * 8;
            int offs = off ^ ((cl & 3) << 4);
            uint4 v = *(const uint4*)&Ct[cl * 72 + offs];
            *(uint4*)&outB[((size_t)(bb * 1024 + n0 + cl)) * 2048 + t0 + off] = v;
        }
    } else {
#pragma unroll
        for (int mi = 0; mi < 4; ++mi)
#pragma unroll
            for (int ni = 0; ni < 2; ++ni) {
                int col = n0 + wave * 32 + ni * 16 + lr;
#pragma unroll
                for (int r = 0; r < 4; ++r) {
                    int row = m0 + mi * 16 + quad * 4 + r;
                    outB[(size_t)row * N + col] = f2bf(acc[mi][ni][r]);
                }
            }
    }
}

__global__ __launch_bounds__(256) void mha_gemm_qkv(
    const uint16_t* __restrict__ A,
    const uint16_t* __restrict__ Wq, const uint16_t* __restrict__ Wk, const uint16_t* __restrict__ Wv,
    uint16_t* __restrict__ Q, uint16_t* __restrict__ K, uint16_t* __restrict__ Vt) {
    switch (blockIdx.z) {
        case 0:  gemm_bk64_body<0>(A, Wq, Q);  break;
        case 1:  gemm_bk64_body<0>(A, Wk, K);  break;
        default: gemm_bk64_body<1>(A, Wv, Vt); break;
    }
}

// ---- out-projection GEMM: 64M x 128N, BK=64, 512 thr / 8 waves ----
// Wave-tile 32x32 (acc 16 VGPR). 2 blocks/CU x 8 waves = 16 waves/CU —
// double the TLP of the 4-wave version at identical LDS (24 KB) and
// per-drain staging; residency, not per-drain MFMA, is what this
// latency-bound pipeline rewards (R9/R11 lessons).
__global__ __launch_bounds__(512) void mha_gemm_out(
    const uint16_t* __restrict__ A, const uint16_t* __restrict__ Wot,
    float* __restrict__ out, const float* __restrict__ bias) {
    const int K = DMODEL, N = DMODEL;
    extern __shared__ char smem[];                  // 24576 B dynamic
    uint16_t* As = (uint16_t*)smem;                 // [64][64]  8 KB
    uint16_t* Bs = (uint16_t*)(smem + 8192);        // [128][64] 16 KB
    const int tid  = threadIdx.x;
    const int wave = tid >> 6;
    const int lane = tid & 63;
    const int m0 = blockIdx.y * 64;
    const int n0 = blockIdx.x * 128;
    const int lr   = lane & 15;
    const int quad = lane >> 4;
    const int wm = wave >> 2, wn = wave & 3;        // 2m x 4n wave grid

    floatx4 acc[2][2];
#pragma unroll
    for (int i = 0; i < 2; ++i)
#pragma unroll
        for (int j = 0; j < 2; ++j) acc[i][j] = (floatx4)0.0f;

    for (int k0 = 0; k0 < K; k0 += 64) {
        {                                           // A: 512 chunks
            int c = tid;
            int r = c >> 3, s = (c & 7) ^ (r & 7);
            const uint16_t* g = A + (size_t)(m0 + r) * K + k0 + s * 8;
            __builtin_amdgcn_global_load_lds((const __attribute__((address_space(1))) void*)g,
                                             (__attribute__((address_space(3))) void*)(As + (size_t)c * 8), 16, 0, 0);
        }
#pragma unroll
        for (int i = 0; i < 2; ++i) {               // B: 1024 chunks
            int c = i * 512 + tid;
            int r = c >> 3, s = (c & 7) ^ (r & 7);
            const uint16_t* g = Wot + (size_t)(n0 + r) * K + k0 + s * 8;
            __builtin_amdgcn_global_load_lds((const __attribute__((address_space(1))) void*)g,
                                             (__attribute__((address_space(3))) void*)(Bs + (size_t)c * 8), 16, 0, 0);
        }
        __syncthreads();
#pragma unroll
        for (int ks = 0; ks < 2; ++ks) {
            bf16x8 af[2], bfr[2];
#pragma unroll
            for (int mi = 0; mi < 2; ++mi) {
                int row = wm * 32 + mi * 16 + lr;
                af[mi] = *(const bf16x8*)&As[row * 64 + (((ks * 4 + quad) ^ (row & 7)) << 3)];
            }
#pragma unroll
            for (int ni = 0; ni < 2; ++ni) {
                int row = wn * 32 + ni * 16 + lr;
                bfr[ni] = *(const bf16x8*)&Bs[row * 64 + (((ks * 4 + quad) ^ (row & 7)) << 3)];
            }
#pragma unroll
            for (int mi = 0; mi < 2; ++mi)
#pragma unroll
                for (int ni = 0; ni < 2; ++ni)
                    acc[mi][ni] = __builtin_amdgcn_mfma_f32_16x16x32_bf16(af[mi], bfr[ni], acc[mi][ni], 0, 0, 0);
        }
        __syncthreads();
    }
#pragma unroll
    for (int mi = 0; mi < 2; ++mi)
#pragma unroll
        for (int ni = 0; ni < 2; ++ni) {
            int col = n0 + wn * 32 + ni * 16 + lr;
            float bv = bias[col];
#pragma unroll
            for (int r = 0; r < 4; ++r) {
                int row = m0 + wm * 32 + mi * 16 + quad * 4 + r;
                out[(size_t)row * N + col] = acc[mi][ni][r] + bv;
            }
        }
}

// ---------------- MFMA flash attention (causal, fixed-base softmax) -------
// 2 waves / 128 thr; 32-row paired q-tiles: block p does q-tile 63-p
// (heavy) then p (light), TH+TL = 33/34 uniformly. Grid (16,32,2) = 1024
// blocks = 4 blocks/CU EXACT (LDS 36 KB) — double the independent
// barrier streams of the 4-wave version at the same waves/CU; the
// per-iter stall interleaves across blocks. XCD = h%8 locality kept.
// Async single-barrier dbuf staging; p = raw v_exp_f32 (W_q pre-scaled);
// Pb chunk-XOR swizzled -> 0 bank conflicts (R12-verified).
__global__ __launch_bounds__(128) void mha_attn_mfma(
    const uint16_t* __restrict__ Q, const uint16_t* __restrict__ K,
    const uint16_t* __restrict__ Vt, uint16_t* __restrict__ ctx) {
    __shared__ alignas(16) uint16_t Ks[2][64 * 64];   // 16 KB
    __shared__ alignas(16) uint16_t Vs[2][64 * 64];   // 16 KB
    __shared__ alignas(16) uint16_t Pb[32 * 64];      // 4 KB (swizzled)

    const int tid  = threadIdx.x;
    const int wave = tid >> 6;
    const int lane = tid & 63;
    const int lr   = lane & 15;
    const int quad = lane >> 4;
    const int h  = blockIdx.x;             // head fastest -> XCD locality
    const int p  = blockIdx.y;             // 0..31
    const int b  = blockIdx.z;
    const int jH = 63 - p, jL = p;         // 32-row q-tiles
    const int TH = (jH >> 1) + 1;
    const int TL = (jL >> 1) + 1;
    const int Ttot = TH + TL;              // 33/34 for every block

    const uint16_t* kbase[4];
    const uint16_t* vbase[4];
#pragma unroll
    for (int i = 0; i < 4; ++i) {
        int c = i * 128 + tid;             // chunk 0..511 (16B each)
        int row = c >> 3, cs = c & 7;
        int csk = cs ^ (row & 7);          // XOR source swizzle; dest linear
        kbase[i] = K  + ((size_t)(b * SEQ_T) + row) * DMODEL + h * DHEAD + csk * 8;
        vbase[i] = Vt + ((size_t)(b * 1024 + h * DHEAD + row)) * 2048 + csk * 8;
    }

    int wrow = jH * 32 + wave * 16;        // this wave's q-row base
    bf16x8 qf0, qf1;
    {
        const size_t qb = ((size_t)(b * SEQ_T) + wrow + lr) * DMODEL + h * DHEAD;
        qf0 = *(const bf16x8*)(Q + qb + quad * 8);
        qf1 = *(const bf16x8*)(Q + qb + 32 + quad * 8);
    }
    floatx4 o[4];
#pragma unroll
    for (int nt = 0; nt < 4; ++nt) o[nt] = (floatx4)0.0f;
    float l[4] = {0.f, 0.f, 0.f, 0.f};

    auto stage = [&](int kv0, int buf) {
#pragma unroll
        for (int i = 0; i < 4; ++i) {
            const uint16_t* gk = kbase[i] + (size_t)kv0 * DMODEL;
            const uint16_t* gv = vbase[i] + kv0;
            uint16_t* lk = &Ks[buf][(i * 128 + wave * 64) * 8];
            uint16_t* lv = &Vs[buf][(i * 128 + wave * 64) * 8];
            __builtin_amdgcn_global_load_lds((const __attribute__((address_space(1))) void*)gk,
                                             (__attribute__((address_space(3))) void*)lk, 16, 0, 0);
            __builtin_amdgcn_global_load_lds((const __attribute__((address_space(1))) void*)gv,
                                             (__attribute__((address_space(3))) void*)lv, 16, 0, 0);
        }
    };
    auto epilogue = [&]() {
#pragma unroll
        for (int r = 0; r < 4; ++r) {
            float v = l[r];
            v += __shfl_xor(v, 1, 64);
            v += __shfl_xor(v, 2, 64);
            v += __shfl_xor(v, 4, 64);
            v += __shfl_xor(v, 8, 64);
            l[r] = 1.f / v;
        }
#pragma unroll
        for (int nt = 0; nt < 4; ++nt)
#pragma unroll
            for (int r = 0; r < 4; ++r) {
                size_t addr = ((size_t)(b * SEQ_T) + wrow + quad * 4 + r) * DMODEL + h * DHEAD + nt * 16 + lr;
                ctx[addr] = f2bf(o[nt][r] * l[r]);
            }
    };

    stage(0, 0);
    __syncthreads();                       // tile 0 ready
    int cur = 0;

    for (int t = 0; t < Ttot; ++t) {
        if (t + 1 < Ttot) {
            int nkv0 = ((t + 1 < TH) ? (t + 1) : (t + 1 - TH)) * 64;
            stage(nkv0, cur ^ 1);          // in flight behind compute
        }
        const int kv0 = ((t < TH) ? t : (t - TH)) * 64;

        floatx4 s[4];
#pragma unroll
        for (int nt = 0; nt < 4; ++nt) {
            s[nt] = (floatx4)0.0f;
            int krow = nt * 16 + lr;
#pragma unroll
            for (int ks = 0; ks < 2; ++ks) {
                bf16x8 kf = *(const bf16x8*)&Ks[cur][krow * 64 + (((ks * 4 + quad) ^ (lr & 7)) * 8)];
                s[nt] = __builtin_amdgcn_mfma_f32_16x16x32_bf16(ks ? qf1 : qf0, kf, s[nt], 0, 0, 0);
            }
        }
        if (kv0 + 63 > wrow) {
#pragma unroll
            for (int nt = 0; nt < 4; ++nt) {
                int kcol = kv0 + nt * 16 + lr;
#pragma unroll
                for (int r = 0; r < 4; ++r) {
                    int qrow = wrow + quad * 4 + r;
                    if (kcol > qrow) s[nt][r] = -3e38f;
                }
            }
        }
        // p = exp2(s) via raw v_exp_f32; truncate to bf16, l kept
        // consistent with the truncated numerator. Pb swizzled by row&7.
#pragma unroll
        for (int nt = 0; nt < 4; ++nt)
#pragma unroll
            for (int r = 0; r < 4; ++r) {
                float pe = __builtin_amdgcn_exp2f(s[nt][r]);
                uint32_t pu = __float_as_uint(pe);
                l[r] += __uint_as_float(pu & 0xffff0000u);
                int row = wave * 16 + quad * 4 + r;
                int cc  = (nt * 2 + (lr >> 3)) ^ (row & 7);
                Pb[row * 64 + cc * 8 + (lr & 7)] = (uint16_t)(pu >> 16);
            }
#pragma unroll
        for (int ks = 0; ks < 2; ++ks) {
            int prow = wave * 16 + lr;
            bf16x8 pfr = *(const bf16x8*)&Pb[prow * 64 + (((ks * 4 + quad) ^ (prow & 7)) * 8)];
#pragma unroll
            for (int nt = 0; nt < 4; ++nt) {
                int vrow = nt * 16 + lr;
                bf16x8 vf = *(const bf16x8*)&Vs[cur][vrow * 64 + (((ks * 4 + quad) ^ (lr & 7)) * 8)];
                o[nt] = __builtin_amdgcn_mfma_f32_16x16x32_bf16(pfr, vf, o[nt], 0, 0, 0);
            }
        }
        if (t == TH - 1) {
            epilogue();
            wrow = jL * 32 + wave * 16;
            const size_t qb = ((size_t)(b * SEQ_T) + wrow + lr) * DMODEL + h * DHEAD;
            qf0 = *(const bf16x8*)(Q + qb + quad * 8);
            qf1 = *(const bf16x8*)(Q + qb + 32 + quad * 8);
#pragma unroll
            for (int nt = 0; nt < 4; ++nt) o[nt] = (floatx4)0.0f;
#pragma unroll
            for (int r = 0; r < 4; ++r) l[r] = 0.f;
        }
        __syncthreads();
        cur ^= 1;
    }
    epilogue();                            // light q-tile output
}

extern "C" void kernel_launch(void* const* d_in, const int* in_sizes, int n_in,
                              void* d_out, int out_size, void* d_ws, size_t ws_size,
                              hipStream_t stream) {
    const float* x  = (const float*)d_in[0];
    const float* Wq = (const float*)d_in[1];
    const float* Wk = (const float*)d_in[2];
    const float* Wv = (const float*)d_in[3];
    const float* Wo = (const float*)d_in[4];
    const float* bo = (const float*)d_in[5];
    float* out = (float*)d_out;

    char* ws = (char*)d_ws;
    const size_t SZ_X = (size_t)4096 * DMODEL * 2;   // 8 MB
    const size_t SZ_W = (size_t)DMODEL * DMODEL * 2; // 2 MB
    size_t off = 0;
    uint16_t* xb  = (uint16_t*)(ws + off); off += SZ_X;
    uint16_t* wqt = (uint16_t*)(ws + off); off += SZ_W;
    uint16_t* wkt = (uint16_t*)(ws + off); off += SZ_W;
    uint16_t* wvt = (uint16_t*)(ws + off); off += SZ_W;
    uint16_t* wot = (uint16_t*)(ws + off); off += SZ_W;
    uint16_t* Qb  = (uint16_t*)(ws + off); off += SZ_X;
    uint16_t* Kb  = (uint16_t*)(ws + off); off += SZ_X;
    uint16_t* Vtb = (uint16_t*)(ws + off); off += SZ_X;  // per-head transposed V
    uint16_t* Cb  = (uint16_t*)(ws + off); off += SZ_X;
    (void)ws_size; (void)in_sizes; (void)n_in; (void)out_size;

    mha_cvt<<<dim3(16, 16, 5), 256, 0, stream>>>(x, xb, Wq, Wk, Wv, Wo, wqt, wkt, wvt, wot);
    mha_gemm_qkv<<<dim3(8, 64, 3), 256, 24576, stream>>>(xb, wqt, wkt, wvt, Qb, Kb, Vtb);
    mha_attn_mfma<<<dim3(NHEAD, 32, 2), 128, 0, stream>>>(Qb, Kb, Vtb, Cb);
    mha_gemm_out<<<dim3(8, 64), 512, 24576, stream>>>(Cb, wot, out, bo);
}

// Round 14
// 177.616 us; speedup vs baseline: 1.0175x; 1.0175x over previous
//
#include <hip/hip_runtime.h>
#include <hip/hip_bf16.h>
#include <cstdint>

// Problem constants: B=2, T=2048, D_IN=D_OUT=1024, H=16, DH=64
#define SEQ_T 2048
#define DMODEL 1024
#define NHEAD 16
#define DHEAD 64

typedef __attribute__((ext_vector_type(8))) __bf16 bf16x8;
typedef __attribute__((ext_vector_type(4))) float floatx4;

static __device__ __forceinline__ uint16_t f2bf(float f) {
    union { float f; uint32_t u; } v; v.f = f;
    uint32_t r = v.u + 0x7FFFu + ((v.u >> 16) & 1u);   // RNE
    return (uint16_t)(r >> 16);
}

// -------- merged fp32->bf16 converts: z<4 weight transpose, z==4 x --------
// W_q (z==0) pre-scaled by 0.125*log2(e): QK^T emits s*C directly, so the
// attention softmax is a single raw v_exp_f32 (__builtin_amdgcn_exp2f).
__global__ void mha_cvt(const float* __restrict__ x, uint16_t* __restrict__ xb,
                        const float* __restrict__ W0, const float* __restrict__ W1,
                        const float* __restrict__ W2, const float* __restrict__ W3,
                        uint16_t* __restrict__ T0, uint16_t* __restrict__ T1,
                        uint16_t* __restrict__ T2, uint16_t* __restrict__ T3) {
    if (blockIdx.z == 4) {
        int base = (blockIdx.y * 16 + blockIdx.x) * 256 + threadIdx.x;
#pragma unroll
        for (int i = 0; i < 16; ++i) {
            int idx = base + i * 65536;
            float4 f = ((const float4*)x)[idx];
            union { uint16_t u[4]; uint64_t v; } o;
            o.u[0] = f2bf(f.x); o.u[1] = f2bf(f.y); o.u[2] = f2bf(f.z); o.u[3] = f2bf(f.w);
            ((uint64_t*)xb)[idx] = o.v;
        }
        return;
    }
    const float* W; uint16_t* Tt; float sc;
    switch (blockIdx.z) {
        case 0: W = W0; Tt = T0; sc = 0.125f * 1.44269504089f; break;
        case 1: W = W1; Tt = T1; sc = 1.f; break;
        case 2: W = W2; Tt = T2; sc = 1.f; break;
        default: W = W3; Tt = T3; sc = 1.f; break;
    }
    __shared__ float tile[64][65];
    const int c  = threadIdx.x & 63;
    const int r0 = threadIdx.x >> 6;
    const int R0 = blockIdx.y * 64, C0 = blockIdx.x * 64;
#pragma unroll
    for (int rr = 0; rr < 16; ++rr) {
        int r = r0 + rr * 4;
        tile[r][c] = W[(size_t)(R0 + r) * DMODEL + C0 + c];
    }
    __syncthreads();
#pragma unroll
    for (int rr = 0; rr < 16; ++rr) {
        int r = r0 + rr * 4;
        Tt[(size_t)(C0 + r) * DMODEL + R0 + c] = f2bf(tile[c][r] * sc);
    }
}

// ------ bf16 MFMA GEMM, 64M x 128N tile, BK=64, B^T input, swizzled ------
// (R10/R12-proven shape; qkv grid 1536 = 6 blocks/CU @ 24 KB dynamic LDS.)
// Swizzle: row r slot q' holds source sub-chunk q'^(r&7) -> 2-way-only.
// MODE 0: bf16 row-major out. MODE 1: Vt[(b*1024+col)*2048+t] via LDS
// transpose reusing staging smem.
template<int MODE>
__device__ __forceinline__ void gemm_bk64_body(
    const uint16_t* __restrict__ A, const uint16_t* __restrict__ Bt,
    uint16_t* __restrict__ outB) {
    const int K = DMODEL, N = DMODEL;
    extern __shared__ char smem[];                  // 24576 B dynamic
    uint16_t* As = (uint16_t*)smem;                 // [64][64]  8 KB
    uint16_t* Bs = (uint16_t*)(smem + 8192);        // [128][64] 16 KB
    const int tid  = threadIdx.x;
    const int wave = tid >> 6;
    const int lane = tid & 63;
    const int m0 = blockIdx.y * 64;
    const int n0 = blockIdx.x * 128;
    const int lr   = lane & 15;
    const int quad = lane >> 4;

    floatx4 acc[4][2];
#pragma unroll
    for (int i = 0; i < 4; ++i)
#pragma unroll
        for (int j = 0; j < 2; ++j) acc[i][j] = (floatx4)0.0f;

    for (int k0 = 0; k0 < K; k0 += 64) {
#pragma unroll
        for (int i = 0; i < 2; ++i) {               // A: 512 chunks (16B)
            int c = i * 256 + tid;
            int r = c >> 3, s = (c & 7) ^ (r & 7);
            const uint16_t* g = A + (size_t)(m0 + r) * K + k0 + s * 8;
            __builtin_amdgcn_global_load_lds((const __attribute__((address_space(1))) void*)g,
                                             (__attribute__((address_space(3))) void*)(As + (size_t)c * 8), 16, 0, 0);
        }
#pragma unroll
        for (int i = 0; i < 4; ++i) {               // B: 1024 chunks
            int c = i * 256 + tid;
            int r = c >> 3, s = (c & 7) ^ (r & 7);
            const uint16_t* g = Bt + (size_t)(n0 + r) * K + k0 + s * 8;
            __builtin_amdgcn_global_load_lds((const __attribute__((address_space(1))) void*)g,
                                             (__attribute__((address_space(3))) void*)(Bs + (size_t)c * 8), 16, 0, 0);
        }
        __syncthreads();
#pragma unroll
        for (int ks = 0; ks < 2; ++ks) {            // two 32-wide k-halves
            bf16x8 af[4], bfr[2];
#pragma unroll
            for (int mi = 0; mi < 4; ++mi) {
                int row = mi * 16 + lr;
                af[mi] = *(const bf16x8*)&As[row * 64 + (((ks * 4 + quad) ^ (row & 7)) << 3)];
            }
#pragma unroll
            for (int ni = 0; ni < 2; ++ni) {
                int row = wave * 32 + ni * 16 + lr;
                bfr[ni] = *(const bf16x8*)&Bs[row * 64 + (((ks * 4 + quad) ^ (row & 7)) << 3)];
            }
#pragma unroll
            for (int mi = 0; mi < 4; ++mi)
#pragma unroll
                for (int ni = 0; ni < 2; ++ni)
                    acc[mi][ni] = __builtin_amdgcn_mfma_f32_16x16x32_bf16(af[mi], bfr[ni], acc[mi][ni], 0, 0, 0);
        }
        __syncthreads();
    }
    if constexpr (MODE == 1) {
        uint16_t* Ct = (uint16_t*)smem;             // [128][72], 18.4 KB
        const int bb = m0 >> 11, t0 = m0 & 2047;
#pragma unroll
        for (int mi = 0; mi < 4; ++mi)
#pragma unroll
            for (int ni = 0; ni < 2; ++ni) {
                int cl = wave * 32 + ni * 16 + lr;
                int tl = mi * 16 + quad * 4;
                int tls = tl ^ ((cl & 3) << 4);     // 2-way-only bank pattern
                union { uint16_t u[4]; uint64_t v8; } pk;
#pragma unroll
                for (int r = 0; r < 4; ++r) pk.u[r] = f2bf(acc[mi][ni][r]);
                *(uint64_t*)&Ct[cl * 72 + tls] = pk.v8;
            }
        __syncthreads();
#pragma unroll
        for (int k = 0; k < 4; ++k) {
            int c = k * 256 + tid;                  // 1024 chunks of 16B
            int cl = c >> 3, off = (c & 7) * 8;
            int offs = off ^ ((cl & 3) << 4);
            uint4 v = *(const uint4*)&Ct[cl * 72 + offs];
            *(uint4*)&outB[((size_t)(bb * 1024 + n0 + cl)) * 2048 + t0 + off] = v;
        }
    } else {
#pragma unroll
        for (int mi = 0; mi < 4; ++mi)
#pragma unroll
            for (int ni = 0; ni < 2; ++ni) {
                int col = n0 + wave * 32 + ni * 16 + lr;
#pragma unroll
                for (int r = 0; r < 4; ++r) {
                    int row = m0 + mi * 16 + quad * 4 + r;
                    outB[(size_t)row * N + col] = f2bf(acc[mi][ni][r]);
                }
            }
    }
}

__global__ __launch_bounds__(256) void mha_gemm_qkv(
    const uint16_t* __restrict__ A,
    const uint16_t* __restrict__ Wq, const uint16_t* __restrict__ Wk, const uint16_t* __restrict__ Wv,
    uint16_t* __restrict__ Q, uint16_t* __restrict__ K, uint16_t* __restrict__ Vt) {
    switch (blockIdx.z) {
        case 0:  gemm_bk64_body<0>(A, Wq, Q);  break;
        case 1:  gemm_bk64_body<0>(A, Wk, K);  break;
        default: gemm_bk64_body<1>(A, Wv, Vt); break;
    }
}

// ---- out-projection GEMM: 64M x 128N, BK=64, 512 thr / 8 waves ----
// (R13-verified win: rest-of-pipeline dropped ~9 µs.) Wave-tile 32x32,
// 2 blocks/CU x 8 waves = 16 waves/CU.
__global__ __launch_bounds__(512) void mha_gemm_out(
    const uint16_t* __restrict__ A, const uint16_t* __restrict__ Wot,
    float* __restrict__ out, const float* __restrict__ bias) {
    const int K = DMODEL, N = DMODEL;
    extern __shared__ char smem[];                  // 24576 B dynamic
    uint16_t* As = (uint16_t*)smem;                 // [64][64]  8 KB
    uint16_t* Bs = (uint16_t*)(smem + 8192);        // [128][64] 16 KB
    const int tid  = threadIdx.x;
    const int wave = tid >> 6;
    const int lane = tid & 63;
    const int m0 = blockIdx.y * 64;
    const int n0 = blockIdx.x * 128;
    const int lr   = lane & 15;
    const int quad = lane >> 4;
    const int wm = wave >> 2, wn = wave & 3;        // 2m x 4n wave grid

    floatx4 acc[2][2];
#pragma unroll
    for (int i = 0; i < 2; ++i)
#pragma unroll
        for (int j = 0; j < 2; ++j) acc[i][j] = (floatx4)0.0f;

    for (int k0 = 0; k0 < K; k0 += 64) {
        {                                           // A: 512 chunks
            int c = tid;
            int r = c >> 3, s = (c & 7) ^ (r & 7);
            const uint16_t* g = A + (size_t)(m0 + r) * K + k0 + s * 8;
            __builtin_amdgcn_global_load_lds((const __attribute__((address_space(1))) void*)g,
                                             (__attribute__((address_space(3))) void*)(As + (size_t)c * 8), 16, 0, 0);
        }
#pragma unroll
        for (int i = 0; i < 2; ++i) {               // B: 1024 chunks
            int c = i * 512 + tid;
            int r = c >> 3, s = (c & 7) ^ (r & 7);
            const uint16_t* g = Wot + (size_t)(n0 + r) * K + k0 + s * 8;
            __builtin_amdgcn_global_load_lds((const __attribute__((address_space(1))) void*)g,
                                             (__attribute__((address_space(3))) void*)(Bs + (size_t)c * 8), 16, 0, 0);
        }
        __syncthreads();
#pragma unroll
        for (int ks = 0; ks < 2; ++ks) {
            bf16x8 af[2], bfr[2];
#pragma unroll
            for (int mi = 0; mi < 2; ++mi) {
                int row = wm * 32 + mi * 16 + lr;
                af[mi] = *(const bf16x8*)&As[row * 64 + (((ks * 4 + quad) ^ (row & 7)) << 3)];
            }
#pragma unroll
            for (int ni = 0; ni < 2; ++ni) {
                int row = wn * 32 + ni * 16 + lr;
                bfr[ni] = *(const bf16x8*)&Bs[row * 64 + (((ks * 4 + quad) ^ (row & 7)) << 3)];
            }
#pragma unroll
            for (int mi = 0; mi < 2; ++mi)
#pragma unroll
                for (int ni = 0; ni < 2; ++ni)
                    acc[mi][ni] = __builtin_amdgcn_mfma_f32_16x16x32_bf16(af[mi], bfr[ni], acc[mi][ni], 0, 0, 0);
        }
        __syncthreads();
    }
#pragma unroll
    for (int mi = 0; mi < 2; ++mi)
#pragma unroll
        for (int ni = 0; ni < 2; ++ni) {
            int col = n0 + wn * 32 + ni * 16 + lr;
            float bv = bias[col];
#pragma unroll
            for (int r = 0; r < 4; ++r) {
                int row = m0 + wm * 32 + mi * 16 + quad * 4 + r;
                out[(size_t)row * N + col] = acc[mi][ni][r] + bv;
            }
        }
}

// ---------------- MFMA flash attention (causal, fixed-base softmax) -------
// R12's proven 4-wave shape: grid (h, p, b) = (16,16,2) = 512 blocks,
// 64-row paired q-tiles (jH=31-p heavy then jL=p light, 33 iters always),
// XCD = h%8 locality, async single-barrier dbuf staging, swizzled Pb
// (0 conflicts), raw v_exp_f32 (W_q pre-scaled by 0.125*log2e).
// NEW: l via MFMA ones-column — l_m = (P·1)_m accumulates in C-layout
// alongside O, reading the SAME truncated-bf16 P from LDS (numerator/
// denominator exactly consistent). Deletes 32 VALU ops/iter and the
// entire epilogue shfl reduction.
__global__ __launch_bounds__(256) void mha_attn_mfma(
    const uint16_t* __restrict__ Q, const uint16_t* __restrict__ K,
    const uint16_t* __restrict__ Vt, uint16_t* __restrict__ ctx) {
    __shared__ alignas(16) uint16_t Ks[2][64 * 64];   // 16 KB
    __shared__ alignas(16) uint16_t Vs[2][64 * 64];   // 16 KB
    __shared__ alignas(16) uint16_t Pb[64 * 64];      // 8 KB (swizzled)

    const int tid  = threadIdx.x;
    const int wave = tid >> 6;
    const int lane = tid & 63;
    const int lr   = lane & 15;
    const int quad = lane >> 4;
    const int h  = blockIdx.x;             // head fastest -> XCD locality
    const int p  = blockIdx.y;             // 0..15
    const int b  = blockIdx.z;
    const int jH = 31 - p, jL = p;         // 64-row q-tiles
    const int TH = jH + 1;
    const int TL = jL + 1;
    const int Ttot = TH + TL;              // 33 for every block

    const uint16_t* kbase[2];
    const uint16_t* vbase[2];
#pragma unroll
    for (int i = 0; i < 2; ++i) {
        int c = i * 256 + tid;             // chunk 0..511 (16B each)
        int row = c >> 3, cs = c & 7;
        int csk = cs ^ (row & 7);          // XOR source swizzle; dest linear
        kbase[i] = K  + ((size_t)(b * SEQ_T) + row) * DMODEL + h * DHEAD + csk * 8;
        vbase[i] = Vt + ((size_t)(b * 1024 + h * DHEAD + row)) * 2048 + csk * 8;
    }

    int wrow = jH * 64 + wave * 16;        // this wave's q-row base
    bf16x8 qf0, qf1;
    {
        const size_t qb = ((size_t)(b * SEQ_T) + wrow + lr) * DMODEL + h * DHEAD;
        qf0 = *(const bf16x8*)(Q + qb + quad * 8);
        qf1 = *(const bf16x8*)(Q + qb + 32 + quad * 8);
    }
    bf16x8 ones;
#pragma unroll
    for (int i = 0; i < 8; ++i) ones[i] = (__bf16)1.0f;

    floatx4 o[4];
#pragma unroll
    for (int nt = 0; nt < 4; ++nt) o[nt] = (floatx4)0.0f;
    floatx4 lacc = (floatx4)0.0f;          // l per row via MFMA ones-column

    auto stage = [&](int kv0, int buf) {
#pragma unroll
        for (int i = 0; i < 2; ++i) {
            const uint16_t* gk = kbase[i] + (size_t)kv0 * DMODEL;
            const uint16_t* gv = vbase[i] + kv0;
            uint16_t* lk = &Ks[buf][(i * 256 + wave * 64) * 8];
            uint16_t* lv = &Vs[buf][(i * 256 + wave * 64) * 8];
            __builtin_amdgcn_global_load_lds((const __attribute__((address_space(1))) void*)gk,
                                             (__attribute__((address_space(3))) void*)lk, 16, 0, 0);
            __builtin_amdgcn_global_load_lds((const __attribute__((address_space(1))) void*)gv,
                                             (__attribute__((address_space(3))) void*)lv, 16, 0, 0);
        }
    };
    auto epilogue = [&]() {
        float linv[4];
#pragma unroll
        for (int r = 0; r < 4; ++r) linv[r] = 1.f / lacc[r];
#pragma unroll
        for (int nt = 0; nt < 4; ++nt)
#pragma unroll
            for (int r = 0; r < 4; ++r) {
                size_t addr = ((size_t)(b * SEQ_T) + wrow + quad * 4 + r) * DMODEL + h * DHEAD + nt * 16 + lr;
                ctx[addr] = f2bf(o[nt][r] * linv[r]);
            }
    };

    stage(0, 0);
    __syncthreads();                       // tile 0 ready
    int cur = 0;

    for (int t = 0; t < Ttot; ++t) {
        if (t + 1 < Ttot) {
            int nkv0 = ((t + 1 < TH) ? (t + 1) : (t + 1 - TH)) * 64;
            stage(nkv0, cur ^ 1);          // in flight behind compute
        }
        const int kv0 = ((t < TH) ? t : (t - TH)) * 64;

        floatx4 s[4];
#pragma unroll
        for (int nt = 0; nt < 4; ++nt) {
            s[nt] = (floatx4)0.0f;
            int krow = nt * 16 + lr;
#pragma unroll
            for (int ks = 0; ks < 2; ++ks) {
                bf16x8 kf = *(const bf16x8*)&Ks[cur][krow * 64 + (((ks * 4 + quad) ^ (lr & 7)) * 8)];
                s[nt] = __builtin_amdgcn_mfma_f32_16x16x32_bf16(ks ? qf1 : qf0, kf, s[nt], 0, 0, 0);
            }
        }
        if (kv0 + 63 > wrow) {
#pragma unroll
            for (int nt = 0; nt < 4; ++nt) {
                int kcol = kv0 + nt * 16 + lr;
#pragma unroll
                for (int r = 0; r < 4; ++r) {
                    int qrow = wrow + quad * 4 + r;
                    if (kcol > qrow) s[nt][r] = -3e38f;
                }
            }
        }
        // p = exp2(s) via raw v_exp_f32 (scale folded into W_q); truncate
        // to bf16 into swizzled Pb. l comes from the PV phase (P·1 MFMA),
        // so no per-score VALU accumulation is needed here.
#pragma unroll
        for (int nt = 0; nt < 4; ++nt)
#pragma unroll
            for (int r = 0; r < 4; ++r) {
                float pe = __builtin_amdgcn_exp2f(s[nt][r]);
                int row = wave * 16 + quad * 4 + r;
                int cc  = (nt * 2 + (lr >> 3)) ^ (row & 7);
                Pb[row * 64 + cc * 8 + (lr & 7)] = (uint16_t)(__float_as_uint(pe) >> 16);
            }
#pragma unroll
        for (int ks = 0; ks < 2; ++ks) {
            int prow = wave * 16 + lr;
            bf16x8 pfr = *(const bf16x8*)&Pb[prow * 64 + (((ks * 4 + quad) ^ (prow & 7)) * 8)];
            lacc = __builtin_amdgcn_mfma_f32_16x16x32_bf16(pfr, ones, lacc, 0, 0, 0);
#pragma unroll
            for (int nt = 0; nt < 4; ++nt) {
                int vrow = nt * 16 + lr;
                bf16x8 vf = *(const bf16x8*)&Vs[cur][vrow * 64 + (((ks * 4 + quad) ^ (lr & 7)) * 8)];
                o[nt] = __builtin_amdgcn_mfma_f32_16x16x32_bf16(pfr, vf, o[nt], 0, 0, 0);
            }
        }
        if (t == TH - 1) {
            epilogue();
            wrow = jL * 64 + wave * 16;
            const size_t qb = ((size_t)(b * SEQ_T) + wrow + lr) * DMODEL + h * DHEAD;
            qf0 = *(const bf16x8*)(Q + qb + quad * 8);
            qf1 = *(const bf16x8*)(Q + qb + 32 + quad * 8);
#pragma unroll
            for (int nt = 0; nt < 4; ++nt) o[nt] = (floatx4)0.0f;
            lacc = (floatx4)0.0f;
        }
        __syncthreads();
        cur ^= 1;
    }
    epilogue();                            // light q-tile output
}

extern "C" void kernel_launch(void* const* d_in, const int* in_sizes, int n_in,
                              void* d_out, int out_size, void* d_ws, size_t ws_size,
                              hipStream_t stream) {
    const float* x  = (const float*)d_in[0];
    const float* Wq = (const float*)d_in[1];
    const float* Wk = (const float*)d_in[2];
    const float* Wv = (const float*)d_in[3];
    const float* Wo = (const float*)d_in[4];
    const float* bo = (const float*)d_in[5];
    float* out = (float*)d_out;

    char* ws = (char*)d_ws;
    const size_t SZ_X = (size_t)4096 * DMODEL * 2;   // 8 MB
    const size_t SZ_W = (size_t)DMODEL * DMODEL * 2; // 2 MB
    size_t off = 0;
    uint16_t* xb  = (uint16_t*)(ws + off); off += SZ_X;
    uint16_t* wqt = (uint16_t*)(ws + off); off += SZ_W;
    uint16_t* wkt = (uint16_t*)(ws + off); off += SZ_W;
    uint16_t* wvt = (uint16_t*)(ws + off); off += SZ_W;
    uint16_t* wot = (uint16_t*)(ws + off); off += SZ_W;
    uint16_t* Qb  = (uint16_t*)(ws + off); off += SZ_X;
    uint16_t* Kb  = (uint16_t*)(ws + off); off += SZ_X;
    uint16_t* Vtb = (uint16_t*)(ws + off); off += SZ_X;  // per-head transposed V
    uint16_t* Cb  = (uint16_t*)(ws + off); off += SZ_X;
    (void)ws_size; (void)in_sizes; (void)n_in; (void)out_size;

    mha_cvt<<<dim3(16, 16, 5), 256, 0, stream>>>(x, xb, Wq, Wk, Wv, Wo, wqt, wkt, wvt, wot);
    mha_gemm_qkv<<<dim3(8, 64, 3), 256, 24576, stream>>>(xb, wqt, wkt, wvt, Qb, Kb, Vtb);
    mha_attn_mfma<<<dim3(NHEAD, 16, 2), 256, 0, stream>>>(Qb, Kb, Vtb, Cb);
    mha_gemm_out<<<dim3(8, 64), 512, 24576, stream>>>(Cb, wot, out, bo);
}